// Round 3
// baseline (211.652 us; speedup 1.0000x reference)
//
#include <hip/hip_runtime.h>
#include <hip/hip_bf16.h>

// Capsule routing; u_hat never materialized. Per iter:
//   vjt: vj = S@W_o -> ssq_part (plain store); t = W_o@vj as bf16 hi/lo
//   route: bb = (t.u^T)/nrm -> softmax_o -> S partials = Wv.u (MFMA bf16)
// R16: shrink the S-partial tensor 4x (touches route/vjt/out).
//  - route grid (B,8): each block owns 4 n-tiles, accumulates S in f32 regs
//    (sacc[8][2] f32x4, static-indexed) across tiles, writes bf16 partials
//    ONCE at block end. Sp: 32 slabs -> 8 slabs (33.5 -> 8.4 MB); total
//    partial-S traffic 134 -> 33.6 MB. Precision slightly better (128-n f32
//    accumulation before one bf16 rounding).
//  - Sp layout [b][o][slab][k]: vjt(1)/k_out read contiguous 16KB per (b,o),
//    8-iter sum (was 32 strided 1KB chunks at 32KB stride).
//  - next-tile u prefetched into regs (T14) so the 1-block/CU route grid
//    hides stage latency under phase1+softmax+phase2.
//  - t A-frags still read directly from global (L2-hot; R15, neutral).
// NOTE (R13): in-kernel grid barriers cost 130us+ on CDNA4 -- keep 6 kernels.
// NOTE (R14/R15): route barrier/tail restructures were NEUTRAL -> route is
// not dominant; this round attacks cross-kernel Sp traffic instead.

constexpr int B = 32, N = 1024, K = 512, O = 32, D = 64, F = 2048;
constexpr int SLABS = 8;  // S-partial slabs per b (route grid.y)
constexpr int ST = 72;    // LDS u16 row stride: 144B, 16B-aligned, b128-friendly
constexpr int STW = 40;   // wvh/wvl row stride (80B, 16B-aligned)

typedef __attribute__((ext_vector_type(8))) short bf16x8;
typedef __attribute__((ext_vector_type(4))) float f32x4;

__device__ inline unsigned int pk_hi(float x, float y) {
  union { __hip_bfloat162 h; unsigned int u; } c;
  c.h = __float22bfloat162_rn(float2{x, y});
  return c.u;
}
__device__ inline unsigned short bf16_1(float x) {
  return (unsigned short)(pk_hi(x, 0.f) & 0xffffu);
}
__device__ inline void split2(float x, unsigned short& h, unsigned short& l) {
  h = bf16_1(x);
  l = bf16_1(x - __uint_as_float((unsigned int)h << 16));
}
__device__ inline float bf2f(unsigned short h) {
  return __uint_as_float((unsigned int)h << 16);
}
__device__ inline int swz(int r) { return ((r >> 3) & 7) << 3; }

__device__ inline bf16x8 frag_row(const unsigned short* p, int r, int k0) {
  return *(const bf16x8*)&p[r * ST + (k0 ^ swz(r))];
}
__device__ inline bf16x8 frag_col(const unsigned short* p, int c, int n0) {
  bf16x8 f;
#pragma unroll
  for (int j = 0; j < 8; j++) {
    int n = n0 + j;
    f[j] = (short)p[n * ST + (c ^ swz(n))];
  }
  return f;
}

// ---- prep: stream u once -> colsum slabs (plain stores) + u_bf (bf16) ----
// grid (B, 32), 256 thr; block handles 32 n-rows.
__global__ __launch_bounds__(256) void k_prep(const float* __restrict__ u,
                                              float* __restrict__ cs_part,
                                              unsigned short* __restrict__ u_bf) {
  __shared__ float4 red[128];
  int b = blockIdx.x, ntile = blockIdx.y, n0 = ntile * 32;
  int tid = threadIdx.x;
  int kq = (tid & 127) * 4, ng = tid >> 7;
  const float* ub = u + ((size_t)b * N + n0 + ng * 16) * K + kq;
  unsigned short* ubf = u_bf + ((size_t)b * N + n0 + ng * 16) * K + kq;
  float4 a = {0.f, 0.f, 0.f, 0.f};
#pragma unroll
  for (int nn = 0; nn < 16; nn++) {
    float4 v = *(const float4*)&ub[(size_t)nn * K];
    a.x += v.x; a.y += v.y; a.z += v.z; a.w += v.w;
    uint2 p;
    p.x = pk_hi(v.x, v.y);
    p.y = pk_hi(v.z, v.w);
    *(uint2*)&ubf[(size_t)nn * K] = p;
  }
  if (ng) red[tid & 127] = a;
  __syncthreads();
  if (!ng) {
    float4 o = red[tid];
    float* cs = cs_part + ((size_t)b * 32 + ntile) * K + kq;
    cs[0] = (a.x + o.x) * (1.f / 32.f);
    cs[1] = (a.y + o.y) * (1.f / 32.f);
    cs[2] = (a.z + o.z) * (1.f / 32.f);
    cs[3] = (a.w + o.w) * (1.f / 32.f);
  }
}

// vj[d]=sum_k s[k]W[k,o*64+d] -> ssq_part[slot*1024+bo]; t = W_o@vj bf16 hi/lo.
// slot 0: s = sum of 32 colsum slabs; else sum of SLABS bf16 partial-S slabs.
__global__ __launch_bounds__(512) void k_vjt(const unsigned short* __restrict__ Sp,
                                             const float* __restrict__ cs_part,
                                             const float* __restrict__ W,
                                             float* __restrict__ ssq_part, int slot,
                                             unsigned short* __restrict__ t_hi,
                                             unsigned short* __restrict__ t_lo) {
  __shared__ __align__(16) float s_s[K];
  __shared__ float red[7][D];
  __shared__ __align__(16) float vs[D];
  int bo = blockIdx.x, b = bo >> 5, o = bo & 31;
  int d = threadIdx.x & 63, ks = threadIdx.x >> 6;  // 8-way k split
  {
    int i = threadIdx.x;  // 512 threads, one k each
    float a = 0.f;
    if (slot == 0) {
      const float* base = cs_part + (size_t)b * 32 * K;
#pragma unroll
      for (int nt = 0; nt < 32; nt++) a += base[(size_t)nt * K + i];
    } else {
      const unsigned short* base = Sp + ((size_t)(b * O + o)) * (SLABS * K);
#pragma unroll
      for (int nt = 0; nt < SLABS; nt++) a += bf2f(base[nt * K + i]);
    }
    s_s[i] = a;
  }
  __syncthreads();
  float acc = 0.f;
  const float* Wc = W + (size_t)o * D + d;
  for (int k = ks * 64; k < ks * 64 + 64; k += 4) {
    acc += s_s[k] * Wc[(size_t)k * F] + s_s[k + 1] * Wc[(size_t)(k + 1) * F] +
           s_s[k + 2] * Wc[(size_t)(k + 2) * F] + s_s[k + 3] * Wc[(size_t)(k + 3) * F];
  }
  if (ks) red[ks - 1][d] = acc;
  __syncthreads();
  if (ks == 0) {
#pragma unroll
    for (int j = 0; j < 7; j++) acc += red[j][d];
    vs[d] = acc;
    float ss = acc * acc;
#pragma unroll
    for (int m = 32; m >= 1; m >>= 1) ss += __shfl_xor(ss, m, 64);
    if (d == 0) ssq_part[slot * 1024 + bo] = ss;
  }
  __syncthreads();
  {  // t phase: wave handles 64 rows, 8 lanes/row (coalesced W reads)
    int wave = threadIdx.x >> 6, lane = threadIdx.x & 63;
    int rr = lane >> 3, dc = lane & 7;
    float4 va = *(const float4*)&vs[dc * 8];
    float4 vb = *(const float4*)&vs[dc * 8 + 4];
#pragma unroll
    for (int i = 0; i < 8; i++) {
      int kk = wave * 64 + i * 8 + rr;
      const float* Wr = W + (size_t)kk * F + o * 64 + dc * 8;
      float4 wa = *(const float4*)Wr;
      float4 wb = *(const float4*)(Wr + 4);
      float p = wa.x * va.x + wa.y * va.y + wa.z * va.z + wa.w * va.w +
                wb.x * vb.x + wb.y * vb.y + wb.z * vb.z + wb.w * vb.w;
      p += __shfl_xor(p, 1, 64);
      p += __shfl_xor(p, 2, 64);
      p += __shfl_xor(p, 4, 64);
      if (dc == 0) {
        unsigned short h, l;
        split2(p, h, l);
        t_hi[(size_t)bo * K + kk] = h;
        t_lo[(size_t)bo * K + kk] = l;
      }
    }
  }
}

// Final: vj from summed bf16 slabs -> squash -> out
__global__ __launch_bounds__(512) void k_out(const unsigned short* __restrict__ Sp,
                                             const float* __restrict__ W,
                                             float* __restrict__ out) {
  __shared__ __align__(16) float s_s[K];
  __shared__ float red[7][D];
  int bo = blockIdx.x, b = bo >> 5, o = bo & 31;
  int d = threadIdx.x & 63, ks = threadIdx.x >> 6;
  {
    const unsigned short* base = Sp + ((size_t)(b * O + o)) * (SLABS * K);
    int i = threadIdx.x;
    float a = 0.f;
#pragma unroll
    for (int nt = 0; nt < SLABS; nt++) a += bf2f(base[nt * K + i]);
    s_s[i] = a;
  }
  __syncthreads();
  float acc = 0.f;
  const float* Wc = W + (size_t)o * D + d;
  for (int k = ks * 64; k < ks * 64 + 64; k += 4) {
    acc += s_s[k] * Wc[(size_t)k * F] + s_s[k + 1] * Wc[(size_t)(k + 1) * F] +
           s_s[k + 2] * Wc[(size_t)(k + 2) * F] + s_s[k + 3] * Wc[(size_t)(k + 3) * F];
  }
  if (ks) red[ks - 1][d] = acc;
  __syncthreads();
  if (ks == 0) {
#pragma unroll
    for (int j = 0; j < 7; j++) acc += red[j][d];
    float ss = acc * acc;
#pragma unroll
    for (int m = 32; m >= 1; m >>= 1) ss += __shfl_xor(ss, m, 64);
    float s = ss + 1e-7f;
    out[(size_t)bo * D + d] = (sqrtf(s) / (0.5f + s)) * acc;
  }
}

// Fused routing step. grid (B, SLABS=8), 256 thr (4 waves); each block runs
// FOUR 32-n tiles sequentially, accumulating S in f32 regs across tiles and
// writing one bf16 partial slab at the end. u tile prefetched into regs.
__global__ __launch_bounds__(256, 1) void k_route(const unsigned short* __restrict__ t_hi_g,
                                                  const unsigned short* __restrict__ t_lo_g,
                                                  const unsigned short* __restrict__ u_bf,
                                                  const float* __restrict__ ssq_part,
                                                  int slot,
                                                  unsigned short* __restrict__ Sp) {
  __shared__ unsigned short u_res[8][32 * ST];            // 36864 B, per-tile u
  __shared__ float wv[32 * 36];                           // 4608 B logits
  __shared__ float psum[8 * 36];                          // reductions
  __shared__ float mbuf[36];
  __shared__ unsigned short wvh[32 * STW], wvl[32 * STW]; // 2x2560 B

  const int b = blockIdx.x, slab = blockIdx.y;
  const int tid = threadIdx.x, lane = tid & 63, wave = tid >> 6;
  const int m = lane & 15, oct = lane >> 4;
  const unsigned short* thg = t_hi_g + (size_t)b * O * K;
  const unsigned short* tlg = t_lo_g + (size_t)b * O * K;

  // staging index: 32 rows x 8 col-groups of 8 u16 (one uint4 per thread)
  const int sr = tid >> 3, sc8 = (tid & 7) * 8;
  const int scs = sc8 ^ swz(sr);  // swizzled LDS col

  // ---- prefetch tile 0 (hides under the norm reduction) ----
  uint4 pf[8];
  {
    const unsigned short* ub0 = u_bf + ((size_t)b * N + (slab * 4) * 32) * K;
#pragma unroll
    for (int ch = 0; ch < 8; ch++)
      pf[ch] = *(const uint4*)&ub0[(size_t)sr * K + ch * 64 + sc8];
  }

  // ---- global-norm reduction from ssq_part (once per launch) ----
  float nrm_inv;
  {
    const float* sp = ssq_part + slot * 1024;
    float sa = 0.f;
#pragma unroll
    for (int j = 0; j < 4; j++) sa += sp[tid + j * 256];
    psum[tid] = sa;
    __syncthreads();
    if (tid < 64) {
      float s = psum[tid] + psum[tid + 64] + psum[tid + 128] + psum[tid + 192];
#pragma unroll
      for (int mm = 32; mm >= 1; mm >>= 1) s += __shfl_xor(s, mm, 64);
      if (tid == 0) mbuf[0] = rsqrtf(fmaxf(s, 1e-12f));
    }
    __syncthreads();
    nrm_inv = mbuf[0];
  }

  const int mo = wave & 1, nt4 = wave >> 1;   // phase-1 16x16 tile coords
  const int mo2 = wave & 1, kp = wave >> 1;   // phase-2 o-half, ktile-pair
  const int o0 = mo2 * 16;

  f32x4 sacc[8][2];  // S accumulators: [kcb][kti], static-indexed (regs)
#pragma unroll
  for (int i = 0; i < 8; i++) {
    sacc[i][0] = f32x4{0.f, 0.f, 0.f, 0.f};
    sacc[i][1] = f32x4{0.f, 0.f, 0.f, 0.f};
  }

  for (int ti = 0; ti < 4; ti++) {
    __syncthreads();  // u_res + wvh/wvl free (prev tile phase 2 done)
#pragma unroll
    for (int ch = 0; ch < 8; ch++)
      *(uint4*)&u_res[ch][sr * ST + scs] = pf[ch];
    __syncthreads();
    if (ti < 3) {  // T14: issue next tile's loads; hide under ph1+softmax+ph2
      const unsigned short* ubn =
          u_bf + ((size_t)b * N + (slab * 4 + ti + 1) * 32) * K;
#pragma unroll
      for (int ch = 0; ch < 8; ch++)
        pf[ch] = *(const uint4*)&ubn[(size_t)sr * K + ch * 64 + sc8];
    }

    // ---- phase 1: bb[32o][32n] = t . u^T  (t from global, no barriers) ----
    f32x4 accb = {0.f, 0.f, 0.f, 0.f};
    for (int kcb = 0; kcb < 8; kcb++) {
      const unsigned short* uc = u_res[kcb];
      const size_t tb = (size_t)(mo * 16 + m) * K + kcb * 64;
#pragma unroll
      for (int ks = 0; ks < 64; ks += 32) {
        bf16x8 ah = *(const bf16x8*)&thg[tb + ks + oct * 8];
        bf16x8 al = *(const bf16x8*)&tlg[tb + ks + oct * 8];
        bf16x8 bh = frag_row(uc, nt4 * 16 + m, ks + oct * 8);
        accb = __builtin_amdgcn_mfma_f32_16x16x32_bf16(ah, bh, accb, 0, 0, 0);
        accb = __builtin_amdgcn_mfma_f32_16x16x32_bf16(al, bh, accb, 0, 0, 0);
      }
    }
#pragma unroll
    for (int r = 0; r < 4; r++)  // D: col=m (n), row=oct*4+r (o)
      wv[(mo * 16 + oct * 4 + r) * 36 + nt4 * 16 + m] = accb[r] * nrm_inv;
    __syncthreads();

    // ---- softmax over o, parallel: n=tid&31, g=tid>>5 owns 4 o's ----
    {
      int n = tid & 31, g = tid >> 5;
      float m4 = -1e30f;
#pragma unroll
      for (int j = 0; j < 4; j++) m4 = fmaxf(m4, wv[(g * 4 + j) * 36 + n]);
      psum[g * 36 + n] = m4;
      __syncthreads();
      if (tid < 32) {
        float mx = psum[tid];
#pragma unroll
        for (int gg = 1; gg < 8; gg++) mx = fmaxf(mx, psum[gg * 36 + tid]);
        mbuf[tid] = mx;
      }
      __syncthreads();
      float mx = mbuf[n];
      float s4 = 0.f;
#pragma unroll
      for (int j = 0; j < 4; j++) {
        float e = __expf(wv[(g * 4 + j) * 36 + n] - mx);
        wv[(g * 4 + j) * 36 + n] = e;
        s4 += e;
      }
      psum[g * 36 + n] = s4;
      __syncthreads();
      if (tid < 32) {
        float s = 0.f;
#pragma unroll
        for (int gg = 0; gg < 8; gg++) s += psum[gg * 36 + tid];
        mbuf[tid] = 1.f / s;
      }
      __syncthreads();
      float inv = mbuf[n];
#pragma unroll
      for (int j = 0; j < 4; j++) {  // Wv -> bf16 hi/lo
        unsigned short h, l;
        split2(wv[(g * 4 + j) * 36 + n] * inv, h, l);
        wvh[(g * 4 + j) * STW + n] = h;
        wvl[(g * 4 + j) * STW + n] = l;
      }
    }
    __syncthreads();

    // ---- phase 2: sacc += Wv . u  (kred = n = 32; u resident, no barriers) --
    {
      bf16x8 a_h = *(const bf16x8*)&wvh[(o0 + m) * STW + oct * 8];
      bf16x8 a_l = *(const bf16x8*)&wvl[(o0 + m) * STW + oct * 8];
#pragma unroll
      for (int kcb = 0; kcb < 8; kcb++) {
        const unsigned short* uc = u_res[kcb];
#pragma unroll
        for (int kti = 0; kti < 2; kti++) {
          int c = (kp * 2 + kti) * 16 + m;  // column within 64-chunk
          bf16x8 bh = frag_col(uc, c, oct * 8);
          sacc[kcb][kti] =
              __builtin_amdgcn_mfma_f32_16x16x32_bf16(a_h, bh, sacc[kcb][kti], 0, 0, 0);
          sacc[kcb][kti] =
              __builtin_amdgcn_mfma_f32_16x16x32_bf16(a_l, bh, sacc[kcb][kti], 0, 0, 0);
        }
      }
    }
  }

  // ---- write S partial slab (once per block): Sp[b][o][slab][k] bf16 ----
#pragma unroll
  for (int kcb = 0; kcb < 8; kcb++) {
#pragma unroll
    for (int kti = 0; kti < 2; kti++) {
      int c = kcb * 64 + (kp * 2 + kti) * 16 + m;
#pragma unroll
      for (int r = 0; r < 4; r++) {  // D: col=m -> kcol, row=oct*4+r -> o
        int orow = o0 + oct * 4 + r;
        Sp[((size_t)(b * O + orow)) * (SLABS * K) + (size_t)slab * K + c] =
            bf16_1(sacc[kcb][kti][r]);
      }
    }
  }
}

extern "C" void kernel_launch(void* const* d_in, const int* in_sizes, int n_in,
                              void* d_out, int out_size, void* d_ws, size_t ws_size,
                              hipStream_t stream) {
  const float* u = (const float*)d_in[0];  // [B,N,K] f32
  const float* W = (const float*)d_in[1];  // [K,F] f32
  float* out = (float*)d_out;              // [B,O,D] f32

  char* ws = (char*)d_ws;
  unsigned short* Sp = (unsigned short*)ws;                 // B*O*SLABS*K u16 (8.4MB)
  unsigned short* u_bf = Sp + (size_t)B * O * SLABS * K;    // B*N*K u16 (33.5MB)
  unsigned short* t_hi = u_bf + (size_t)B * N * K;          // B*O*K u16 (1MB)
  unsigned short* t_lo = t_hi + (size_t)B * O * K;          // B*O*K u16
  float* cs_part = (float*)(t_lo + (size_t)B * O * K);      // B*32*K f32 (2MB)
  float* ssq_part = cs_part + (size_t)B * 32 * K;           // 2048 f32

  k_prep<<<dim3(B, 32), 256, 0, stream>>>(u, cs_part, u_bf);
  k_vjt<<<B * O, 512, 0, stream>>>(Sp, cs_part, W, ssq_part, 0, t_hi, t_lo);
  k_route<<<dim3(B, SLABS), 256, 0, stream>>>(t_hi, t_lo, u_bf, ssq_part, 0, Sp);
  k_vjt<<<B * O, 512, 0, stream>>>(Sp, cs_part, W, ssq_part, 1, t_hi, t_lo);
  k_route<<<dim3(B, SLABS), 256, 0, stream>>>(t_hi, t_lo, u_bf, ssq_part, 1, Sp);
  k_out<<<B * O, 512, 0, stream>>>(Sp, W, out);
}

// Round 6
// 198.499 us; speedup vs baseline: 1.0663x; 1.0663x over previous
//
#include <hip/hip_runtime.h>
#include <hip/hip_bf16.h>

// Capsule routing; u_hat never materialized. Per iter:
//   vjt: vj = S@W_o -> ssq_part (plain store); t = W_o@vj as bf16 hi/lo
//   route: bb = (t.u^T)/nrm -> softmax_o -> Spart[nt] = Wv.u (MFMA bf16 hi/lo)
// R19 = R17 design with the one novel construct (f32->u16 LDS alias) removed
// after two container failures on R17's exact source (audited in-bounds; most
// likely infra, but never resubmit identical bytes twice).
//  - softmax now fully in-register: bb stays in accb regs; only the two 8-way
//    cross-thread reductions (max, sum) go through a 1KB f32 psum; Wv written
//    once, directly typed bf16 hi/lo. No f32 logit LDS round-trip, no alias.
//    Identical FP order -> bit-identical output.
//  - u_res persistent: 8 chunks, STU=64 + per-row XOR swizzle (32KB, no pad).
//    Staged once/block; phase 2 barrier-free, u read once (-33.5MB/launch).
//  - t read directly from global in phase 1 (L2-hot 64KB/b; R15 neutral-safe).
//  - LDS 38,932B -> 4 blocks/CU, grid (B,32)=1024 all co-resident.
//  - Barriers/block ~8 (baseline ~38).
// k_prep / k_vjt / k_out / launcher VERBATIM Round-0 (clean A/B on route).
// NOTE (R16): route time ~ 1/occupancy (41us @ 1 blk/CU, MfmaUtil 3.3%);
// memory bytes are L3-absorbed; occupancy is the controlling variable.
// NOTE (R13): in-kernel grid barriers cost 130us+ on CDNA4 -- keep 6 kernels.

constexpr int B = 32, N = 1024, K = 512, O = 32, D = 64, F = 2048;
constexpr int NT = 32;   // n-tile -> 32 slabs per b
constexpr int STU = 64;  // u_res row stride (u16): XOR-swizzled, zero padding
constexpr int STW = 40;  // wvh/wvl row stride (80B, 16B-aligned)

typedef __attribute__((ext_vector_type(8))) short bf16x8;
typedef __attribute__((ext_vector_type(4))) float f32x4;

__device__ inline unsigned int pk_hi(float x, float y) {
  union { __hip_bfloat162 h; unsigned int u; } c;
  c.h = __float22bfloat162_rn(float2{x, y});
  return c.u;
}
__device__ inline unsigned short bf16_1(float x) {
  return (unsigned short)(pk_hi(x, 0.f) & 0xffffu);
}
__device__ inline void split2(float x, unsigned short& h, unsigned short& l) {
  h = bf16_1(x);
  l = bf16_1(x - __uint_as_float((unsigned int)h << 16));
}
__device__ inline float bf2f(unsigned short h) {
  return __uint_as_float((unsigned int)h << 16);
}

// u_res accessors: row r, XOR swizzle on 8-u16 granules (bits 3..5 of col).
__device__ inline bf16x8 frag_row_u(const unsigned short* p, int r, int k0) {
  return *(const bf16x8*)&p[r * STU + (k0 ^ ((r & 7) << 3))];
}
__device__ inline bf16x8 frag_col_u(const unsigned short* p, int c, int n0) {
  bf16x8 f;
#pragma unroll
  for (int j = 0; j < 8; j++) {
    int n = n0 + j;
    f[j] = (short)p[n * STU + (c ^ ((n & 7) << 3))];
  }
  return f;
}

// ---- prep: stream u once -> colsum slabs (plain stores) + u_bf (bf16) ----
// grid (B, 32), 256 thr; block handles 32 n-rows.
__global__ __launch_bounds__(256) void k_prep(const float* __restrict__ u,
                                              float* __restrict__ cs_part,
                                              unsigned short* __restrict__ u_bf) {
  __shared__ float4 red[128];
  int b = blockIdx.x, ntile = blockIdx.y, n0 = ntile * 32;
  int tid = threadIdx.x;
  int kq = (tid & 127) * 4, ng = tid >> 7;
  const float* ub = u + ((size_t)b * N + n0 + ng * 16) * K + kq;
  unsigned short* ubf = u_bf + ((size_t)b * N + n0 + ng * 16) * K + kq;
  float4 a = {0.f, 0.f, 0.f, 0.f};
#pragma unroll
  for (int nn = 0; nn < 16; nn++) {
    float4 v = *(const float4*)&ub[(size_t)nn * K];
    a.x += v.x; a.y += v.y; a.z += v.z; a.w += v.w;
    uint2 p;
    p.x = pk_hi(v.x, v.y);
    p.y = pk_hi(v.z, v.w);
    *(uint2*)&ubf[(size_t)nn * K] = p;
  }
  if (ng) red[tid & 127] = a;
  __syncthreads();
  if (!ng) {
    float4 o = red[tid];
    float* cs = cs_part + ((size_t)b * 32 + ntile) * K + kq;
    cs[0] = (a.x + o.x) * (1.f / 32.f);
    cs[1] = (a.y + o.y) * (1.f / 32.f);
    cs[2] = (a.z + o.z) * (1.f / 32.f);
    cs[3] = (a.w + o.w) * (1.f / 32.f);
  }
}

// vj[d]=sum_k s[k]W[k,o*64+d] -> ssq_part[slot*1024+bo]; t = W_o@vj bf16 hi/lo.
// slot 0: s = sum of 32 colsum slabs; else sum of 32 bf16 partial-S slabs.
__global__ __launch_bounds__(512) void k_vjt(const unsigned short* __restrict__ Sp,
                                             const float* __restrict__ cs_part,
                                             const float* __restrict__ W,
                                             float* __restrict__ ssq_part, int slot,
                                             unsigned short* __restrict__ t_hi,
                                             unsigned short* __restrict__ t_lo) {
  __shared__ __align__(16) float s_s[K];
  __shared__ float red[7][D];
  __shared__ __align__(16) float vs[D];
  int bo = blockIdx.x, b = bo >> 5, o = bo & 31;
  int d = threadIdx.x & 63, ks = threadIdx.x >> 6;  // 8-way k split
  {
    int i = threadIdx.x;  // 512 threads, one k each
    float a = 0.f;
    if (slot == 0) {
      const float* base = cs_part + (size_t)b * 32 * K;
#pragma unroll
      for (int nt = 0; nt < 32; nt++) a += base[(size_t)nt * K + i];
    } else {
      const unsigned short* base = Sp + ((size_t)b * NT * O + o) * K;
#pragma unroll
      for (int nt = 0; nt < NT; nt++) a += bf2f(base[(size_t)nt * O * K + i]);
    }
    s_s[i] = a;
  }
  __syncthreads();
  float acc = 0.f;
  const float* Wc = W + (size_t)o * D + d;
  for (int k = ks * 64; k < ks * 64 + 64; k += 4) {
    acc += s_s[k] * Wc[(size_t)k * F] + s_s[k + 1] * Wc[(size_t)(k + 1) * F] +
           s_s[k + 2] * Wc[(size_t)(k + 2) * F] + s_s[k + 3] * Wc[(size_t)(k + 3) * F];
  }
  if (ks) red[ks - 1][d] = acc;
  __syncthreads();
  if (ks == 0) {
#pragma unroll
    for (int j = 0; j < 7; j++) acc += red[j][d];
    vs[d] = acc;
    float ss = acc * acc;
#pragma unroll
    for (int m = 32; m >= 1; m >>= 1) ss += __shfl_xor(ss, m, 64);
    if (d == 0) ssq_part[slot * 1024 + bo] = ss;
  }
  __syncthreads();
  {  // t phase: wave handles 64 rows, 8 lanes/row (coalesced W reads)
    int wave = threadIdx.x >> 6, lane = threadIdx.x & 63;
    int rr = lane >> 3, dc = lane & 7;
    float4 va = *(const float4*)&vs[dc * 8];
    float4 vb = *(const float4*)&vs[dc * 8 + 4];
#pragma unroll
    for (int i = 0; i < 8; i++) {
      int kk = wave * 64 + i * 8 + rr;
      const float* Wr = W + (size_t)kk * F + o * 64 + dc * 8;
      float4 wa = *(const float4*)Wr;
      float4 wb = *(const float4*)(Wr + 4);
      float p = wa.x * va.x + wa.y * va.y + wa.z * va.z + wa.w * va.w +
                wb.x * vb.x + wb.y * vb.y + wb.z * vb.z + wb.w * vb.w;
      p += __shfl_xor(p, 1, 64);
      p += __shfl_xor(p, 2, 64);
      p += __shfl_xor(p, 4, 64);
      if (dc == 0) {
        unsigned short h, l;
        split2(p, h, l);
        t_hi[(size_t)bo * K + kk] = h;
        t_lo[(size_t)bo * K + kk] = l;
      }
    }
  }
}

// Final: vj from summed bf16 slabs -> squash -> out
__global__ __launch_bounds__(512) void k_out(const unsigned short* __restrict__ Sp,
                                             const float* __restrict__ W,
                                             float* __restrict__ out) {
  __shared__ __align__(16) float s_s[K];
  __shared__ float red[7][D];
  int bo = blockIdx.x, b = bo >> 5, o = bo & 31;
  int d = threadIdx.x & 63, ks = threadIdx.x >> 6;
  {
    const unsigned short* base = Sp + ((size_t)b * NT * O + o) * K;
    int i = threadIdx.x;
    float a = 0.f;
#pragma unroll
    for (int nt = 0; nt < NT; nt++) a += bf2f(base[(size_t)nt * O * K + i]);
    s_s[i] = a;
  }
  __syncthreads();
  float acc = 0.f;
  const float* Wc = W + (size_t)o * D + d;
  for (int k = ks * 64; k < ks * 64 + 64; k += 4) {
    acc += s_s[k] * Wc[(size_t)k * F] + s_s[k + 1] * Wc[(size_t)(k + 1) * F] +
           s_s[k + 2] * Wc[(size_t)(k + 2) * F] + s_s[k + 3] * Wc[(size_t)(k + 3) * F];
  }
  if (ks) red[ks - 1][d] = acc;
  __syncthreads();
  if (ks == 0) {
#pragma unroll
    for (int j = 0; j < 7; j++) acc += red[j][d];
    float ss = acc * acc;
#pragma unroll
    for (int m = 32; m >= 1; m >>= 1) ss += __shfl_xor(ss, m, 64);
    float s = ss + 1e-7f;
    out[(size_t)bo * D + d] = (sqrtf(s) / (0.5f + s)) * acc;
  }
}

// Fused routing step, 32-n tile, 256 thr (4 waves), grid (B,32)=1024 blocks.
// LDS 38,932B -> 4 blocks/CU (all 1024 co-resident, 16 waves/CU).
// u_res persistent (XOR-swizzled, staged once); t direct from global;
// softmax in-register (bb never leaves accb; only max/sum partials in LDS).
__global__ __launch_bounds__(256, 4) void k_route(const unsigned short* __restrict__ t_hi_g,
                                                  const unsigned short* __restrict__ t_lo_g,
                                                  const unsigned short* __restrict__ u_bf,
                                                  const float* __restrict__ ssq_part,
                                                  int slot,
                                                  unsigned short* __restrict__ Sp) {
  __shared__ unsigned short u_res[8][32 * STU];            // 32768 B
  __shared__ unsigned short wvh[32 * STW], wvl[32 * STW];  // 2x2560 B (typed)
  __shared__ float psum[256];                              // 1024 B
  __shared__ float nb;                                     // 4 B

  const int b = blockIdx.x, tile = blockIdx.y;
  const int tid = threadIdx.x, lane = tid & 63, wave = tid >> 6;
  const int m = lane & 15, oct = lane >> 4;
  const unsigned short* ubf = u_bf + ((size_t)b * N + tile * 32) * K;
  const unsigned short* thg = t_hi_g + (size_t)b * O * K;
  const unsigned short* tlg = t_lo_g + (size_t)b * O * K;

  // staging index: 32 rows x 8 col-groups of 8 u16 (one uint4 per thread)
  const int sr = tid >> 3, sc8 = (tid & 7) * 8;
  const int scs = sc8 ^ ((sr & 7) << 3);  // XOR-swizzled col

  // ---- stage full u slab once (disjoint cells; barrier below covers it) ----
#pragma unroll
  for (int ch = 0; ch < 8; ch++)
    *(uint4*)&u_res[ch][sr * STU + scs] =
        *(const uint4*)&ubf[(size_t)sr * K + ch * 64 + sc8];

  // ---- global-norm reduction from ssq_part (overlaps staging latency) ----
  float nrm_inv;
  {
    const float* sp = ssq_part + slot * 1024;
    float sa = 0.f;
#pragma unroll
    for (int j = 0; j < 4; j++) sa += sp[tid + j * 256];
    psum[tid] = sa;
    __syncthreads();  // psum ready AND u_res staged
    if (tid < 64) {
      float s = psum[tid] + psum[tid + 64] + psum[tid + 128] + psum[tid + 192];
#pragma unroll
      for (int mm = 32; mm >= 1; mm >>= 1) s += __shfl_xor(s, mm, 64);
      if (tid == 0) nb = rsqrtf(fmaxf(s, 1e-12f));
    }
    __syncthreads();
    nrm_inv = nb;
  }

  // ---- phase 1: bb[32o][32n] = t . u^T  (t from global, NO barriers) ----
  // thread holds o = mo*16 + oct*4 + r (r=0..3), n = nt4*16 + m.
  const int mo = wave & 1, nt4 = wave >> 1;  // o-half, n-half (16x16 tiles)
  f32x4 accb = {0.f, 0.f, 0.f, 0.f};
  for (int kcb = 0; kcb < 8; kcb++) {
    const unsigned short* uc = u_res[kcb];
    const size_t tb = (size_t)(mo * 16 + m) * K + (size_t)kcb * 64;
#pragma unroll
    for (int ks = 0; ks < 64; ks += 32) {
      bf16x8 ah = *(const bf16x8*)&thg[tb + ks + oct * 8];
      bf16x8 al = *(const bf16x8*)&tlg[tb + ks + oct * 8];
      bf16x8 bh = frag_row_u(uc, nt4 * 16 + m, ks + oct * 8);
      accb = __builtin_amdgcn_mfma_f32_16x16x32_bf16(ah, bh, accb, 0, 0, 0);
      accb = __builtin_amdgcn_mfma_f32_16x16x32_bf16(al, bh, accb, 0, 0, 0);
    }
  }

  // ---- softmax over o, in-register; psum rows indexed g = mo*4+oct,
  // so group g covers o-block {4g..4g+3} (same partition/order as baseline;
  // ascending g == ascending o-block -> bit-identical max/sum order). ----
  {
    const int n = nt4 * 16 + m, g = mo * 4 + oct;
    float v4[4];
#pragma unroll
    for (int r = 0; r < 4; r++) v4[r] = accb[r] * nrm_inv;
    float m4 = fmaxf(fmaxf(v4[0], v4[1]), fmaxf(v4[2], v4[3]));
    psum[g * 32 + n] = m4;
    __syncthreads();
    float mx = psum[n];
#pragma unroll
    for (int gg = 1; gg < 8; gg++) mx = fmaxf(mx, psum[gg * 32 + n]);
    __syncthreads();  // all max reads done before psum reuse
    float e[4], s4 = 0.f;
#pragma unroll
    for (int r = 0; r < 4; r++) {
      e[r] = __expf(v4[r] - mx);
      s4 += e[r];
    }
    psum[g * 32 + n] = s4;
    __syncthreads();
    float s = 0.f;
#pragma unroll
    for (int gg = 0; gg < 8; gg++) s += psum[gg * 32 + n];
    float inv = 1.f / s;
#pragma unroll
    for (int r = 0; r < 4; r++) {  // Wv -> typed bf16 hi/lo buffers
      unsigned short h, l;
      split2(e[r] * inv, h, l);
      wvh[(mo * 16 + oct * 4 + r) * STW + n] = h;
      wvl[(mo * 16 + oct * 4 + r) * STW + n] = l;
    }
  }
  __syncthreads();

  // ---- phase 2: Spart = Wv . u  (kred = n = 32; u resident, NO barriers) ----
  const int kp = wave >> 1;
  const int o0 = (wave & 1) * 16;
  bf16x8 a_h = *(const bf16x8*)&wvh[(o0 + m) * STW + oct * 8];
  bf16x8 a_l = *(const bf16x8*)&wvl[(o0 + m) * STW + oct * 8];
  unsigned short* Sb = Sp + ((size_t)b * NT + tile) * O * K;
  for (int kcb = 0; kcb < 8; kcb++) {
    const unsigned short* uc = u_res[kcb];
#pragma unroll
    for (int kt = kp * 2; kt < kp * 2 + 2; kt++) {
      int c = kt * 16 + m;  // column within chunk
      bf16x8 bh = frag_col_u(uc, c, oct * 8);
      f32x4 acs = {0.f, 0.f, 0.f, 0.f};
      acs = __builtin_amdgcn_mfma_f32_16x16x32_bf16(a_h, bh, acs, 0, 0, 0);
      acs = __builtin_amdgcn_mfma_f32_16x16x32_bf16(a_l, bh, acs, 0, 0, 0);
#pragma unroll
      for (int r = 0; r < 4; r++)  // D: col=m -> kcol, row=oct*4+r -> o
        Sb[(size_t)(o0 + oct * 4 + r) * K + kcb * 64 + c] = bf16_1(acs[r]);
    }
  }
}

extern "C" void kernel_launch(void* const* d_in, const int* in_sizes, int n_in,
                              void* d_out, int out_size, void* d_ws, size_t ws_size,
                              hipStream_t stream) {
  const float* u = (const float*)d_in[0];  // [B,N,K] f32
  const float* W = (const float*)d_in[1];  // [K,F] f32
  float* out = (float*)d_out;              // [B,O,D] f32

  char* ws = (char*)d_ws;
  unsigned short* Sp = (unsigned short*)ws;              // B*NT*O*K u16 (33.5MB)
  unsigned short* u_bf = Sp + (size_t)B * NT * O * K;    // B*N*K u16 (33.5MB)
  unsigned short* t_hi = u_bf + (size_t)B * N * K;       // B*O*K u16 (1MB)
  unsigned short* t_lo = t_hi + (size_t)B * O * K;       // B*O*K u16
  float* cs_part = (float*)(t_lo + (size_t)B * O * K);   // B*32*K f32 (2MB)
  float* ssq_part = cs_part + (size_t)B * 32 * K;        // 2048 f32

  k_prep<<<dim3(B, 32), 256, 0, stream>>>(u, cs_part, u_bf);
  k_vjt<<<B * O, 512, 0, stream>>>(Sp, cs_part, W, ssq_part, 0, t_hi, t_lo);
  k_route<<<dim3(B, NT), 256, 0, stream>>>(t_hi, t_lo, u_bf, ssq_part, 0, Sp);
  k_vjt<<<B * O, 512, 0, stream>>>(Sp, cs_part, W, ssq_part, 1, t_hi, t_lo);
  k_route<<<dim3(B, NT), 256, 0, stream>>>(t_hi, t_lo, u_bf, ssq_part, 1, Sp);
  k_out<<<B * O, 512, 0, stream>>>(Sp, W, out);
}

// Round 7
// 183.678 us; speedup vs baseline: 1.1523x; 1.0807x over previous
//
#include <hip/hip_runtime.h>
#include <hip/hip_bf16.h>

// Capsule routing; u_hat never materialized. Per iter:
//   vjt: vj = S@W_o -> ssq_part (plain store); t = W_o@vj as bf16 hi/lo
//   route: bb = (t.u^T)/nrm -> softmax_o -> Spart[nt] = Wv.u (MFMA bf16 hi/lo)
// R20 = EXACT Round-0 skeleton (best measured, 185.7us) with ONE change:
// phase-2 B-fragments via transpose-on-store instead of frag_col.
//  - Old: stage u row-major, then per frag 8x ds_read_u16 + pack (16 reads +
//    ~32 VALU per thread/chunk; likely most of route's 1.34M bank conflicts).
//  - New: staging writes the chunk TRANSPOSED u_T[c][n], stride 36 u16 --
//    fits the existing u_hi buffer exactly (64*36 == 32*72). Frag read =
//    two aligned b64 loads of contiguous n (bank-free: 18m mod 32 distinct,
//    +4*oct -> 2-way). Write side ~4-way on 8 u16 stores (acceptable).
//  - Identical FP order -> bit-identical output. LDS/occupancy unchanged.
// Lessons encoded: R14/R15/R19 barrier/staging rewrites all regressed ->
// at 16 waves/CU the baseline barriers are hidden; do NOT restructure.
// R16: route time ~ 1/occupancy; keep grid (B,32) @ 4 blocks/CU.
// NOTE (R13): in-kernel grid barriers cost 130us+ on CDNA4 -- keep 6 kernels.

constexpr int B = 32, N = 1024, K = 512, O = 32, D = 64, F = 2048;
constexpr int NT = 32;   // n-tile -> 32 slabs per b
constexpr int ST = 72;   // LDS u16 row stride: 144B, 16B-aligned, b128-friendly
constexpr int STT = 36;  // u_T col stride (u16): 72B, b64-aligned

typedef __attribute__((ext_vector_type(8))) short bf16x8;
typedef __attribute__((ext_vector_type(4))) float f32x4;

__device__ inline unsigned int pk_hi(float x, float y) {
  union { __hip_bfloat162 h; unsigned int u; } c;
  c.h = __float22bfloat162_rn(float2{x, y});
  return c.u;
}
__device__ inline unsigned short bf16_1(float x) {
  return (unsigned short)(pk_hi(x, 0.f) & 0xffffu);
}
__device__ inline void split2(float x, unsigned short& h, unsigned short& l) {
  h = bf16_1(x);
  l = bf16_1(x - __uint_as_float((unsigned int)h << 16));
}
__device__ inline float bf2f(unsigned short h) {
  return __uint_as_float((unsigned int)h << 16);
}
__device__ inline int swz(int r) { return ((r >> 3) & 7) << 3; }

__device__ inline bf16x8 frag_row(const unsigned short* p, int r, int k0) {
  return *(const bf16x8*)&p[r * ST + (k0 ^ swz(r))];
}

// ---- prep: stream u once -> colsum slabs (plain stores) + u_bf (bf16) ----
// grid (B, 32), 256 thr; block handles 32 n-rows.
__global__ __launch_bounds__(256) void k_prep(const float* __restrict__ u,
                                              float* __restrict__ cs_part,
                                              unsigned short* __restrict__ u_bf) {
  __shared__ float4 red[128];
  int b = blockIdx.x, ntile = blockIdx.y, n0 = ntile * 32;
  int tid = threadIdx.x;
  int kq = (tid & 127) * 4, ng = tid >> 7;
  const float* ub = u + ((size_t)b * N + n0 + ng * 16) * K + kq;
  unsigned short* ubf = u_bf + ((size_t)b * N + n0 + ng * 16) * K + kq;
  float4 a = {0.f, 0.f, 0.f, 0.f};
#pragma unroll
  for (int nn = 0; nn < 16; nn++) {
    float4 v = *(const float4*)&ub[(size_t)nn * K];
    a.x += v.x; a.y += v.y; a.z += v.z; a.w += v.w;
    uint2 p;
    p.x = pk_hi(v.x, v.y);
    p.y = pk_hi(v.z, v.w);
    *(uint2*)&ubf[(size_t)nn * K] = p;
  }
  if (ng) red[tid & 127] = a;
  __syncthreads();
  if (!ng) {
    float4 o = red[tid];
    float* cs = cs_part + ((size_t)b * 32 + ntile) * K + kq;
    cs[0] = (a.x + o.x) * (1.f / 32.f);
    cs[1] = (a.y + o.y) * (1.f / 32.f);
    cs[2] = (a.z + o.z) * (1.f / 32.f);
    cs[3] = (a.w + o.w) * (1.f / 32.f);
  }
}

// vj[d]=sum_k s[k]W[k,o*64+d] -> ssq_part[slot*1024+bo]; t = W_o@vj bf16 hi/lo.
// slot 0: s = sum of 32 colsum slabs; else sum of 32 bf16 partial-S slabs.
__global__ __launch_bounds__(512) void k_vjt(const unsigned short* __restrict__ Sp,
                                             const float* __restrict__ cs_part,
                                             const float* __restrict__ W,
                                             float* __restrict__ ssq_part, int slot,
                                             unsigned short* __restrict__ t_hi,
                                             unsigned short* __restrict__ t_lo) {
  __shared__ __align__(16) float s_s[K];
  __shared__ float red[7][D];
  __shared__ __align__(16) float vs[D];
  int bo = blockIdx.x, b = bo >> 5, o = bo & 31;
  int d = threadIdx.x & 63, ks = threadIdx.x >> 6;  // 8-way k split
  {
    int i = threadIdx.x;  // 512 threads, one k each
    float a = 0.f;
    if (slot == 0) {
      const float* base = cs_part + (size_t)b * 32 * K;
#pragma unroll
      for (int nt = 0; nt < 32; nt++) a += base[(size_t)nt * K + i];
    } else {
      const unsigned short* base = Sp + ((size_t)b * NT * O + o) * K;
#pragma unroll
      for (int nt = 0; nt < NT; nt++) a += bf2f(base[(size_t)nt * O * K + i]);
    }
    s_s[i] = a;
  }
  __syncthreads();
  float acc = 0.f;
  const float* Wc = W + (size_t)o * D + d;
  for (int k = ks * 64; k < ks * 64 + 64; k += 4) {
    acc += s_s[k] * Wc[(size_t)k * F] + s_s[k + 1] * Wc[(size_t)(k + 1) * F] +
           s_s[k + 2] * Wc[(size_t)(k + 2) * F] + s_s[k + 3] * Wc[(size_t)(k + 3) * F];
  }
  if (ks) red[ks - 1][d] = acc;
  __syncthreads();
  if (ks == 0) {
#pragma unroll
    for (int j = 0; j < 7; j++) acc += red[j][d];
    vs[d] = acc;
    float ss = acc * acc;
#pragma unroll
    for (int m = 32; m >= 1; m >>= 1) ss += __shfl_xor(ss, m, 64);
    if (d == 0) ssq_part[slot * 1024 + bo] = ss;
  }
  __syncthreads();
  {  // t phase: wave handles 64 rows, 8 lanes/row (coalesced W reads)
    int wave = threadIdx.x >> 6, lane = threadIdx.x & 63;
    int rr = lane >> 3, dc = lane & 7;
    float4 va = *(const float4*)&vs[dc * 8];
    float4 vb = *(const float4*)&vs[dc * 8 + 4];
#pragma unroll
    for (int i = 0; i < 8; i++) {
      int kk = wave * 64 + i * 8 + rr;
      const float* Wr = W + (size_t)kk * F + o * 64 + dc * 8;
      float4 wa = *(const float4*)Wr;
      float4 wb = *(const float4*)(Wr + 4);
      float p = wa.x * va.x + wa.y * va.y + wa.z * va.z + wa.w * va.w +
                wb.x * vb.x + wb.y * vb.y + wb.z * vb.z + wb.w * vb.w;
      p += __shfl_xor(p, 1, 64);
      p += __shfl_xor(p, 2, 64);
      p += __shfl_xor(p, 4, 64);
      if (dc == 0) {
        unsigned short h, l;
        split2(p, h, l);
        t_hi[(size_t)bo * K + kk] = h;
        t_lo[(size_t)bo * K + kk] = l;
      }
    }
  }
}

// Final: vj from summed bf16 slabs -> squash -> out
__global__ __launch_bounds__(512) void k_out(const unsigned short* __restrict__ Sp,
                                             const float* __restrict__ W,
                                             float* __restrict__ out) {
  __shared__ __align__(16) float s_s[K];
  __shared__ float red[7][D];
  int bo = blockIdx.x, b = bo >> 5, o = bo & 31;
  int d = threadIdx.x & 63, ks = threadIdx.x >> 6;
  {
    const unsigned short* base = Sp + ((size_t)b * NT * O + o) * K;
    int i = threadIdx.x;
    float a = 0.f;
#pragma unroll
    for (int nt = 0; nt < NT; nt++) a += bf2f(base[(size_t)nt * O * K + i]);
    s_s[i] = a;
  }
  __syncthreads();
  float acc = 0.f;
  const float* Wc = W + (size_t)o * D + d;
  for (int k = ks * 64; k < ks * 64 + 64; k += 4) {
    acc += s_s[k] * Wc[(size_t)k * F] + s_s[k + 1] * Wc[(size_t)(k + 1) * F] +
           s_s[k + 2] * Wc[(size_t)(k + 2) * F] + s_s[k + 3] * Wc[(size_t)(k + 3) * F];
  }
  if (ks) red[ks - 1][d] = acc;
  __syncthreads();
  if (ks == 0) {
#pragma unroll
    for (int j = 0; j < 7; j++) acc += red[j][d];
    float ss = acc * acc;
#pragma unroll
    for (int m = 32; m >= 1; m >>= 1) ss += __shfl_xor(ss, m, 64);
    float s = ss + 1e-7f;
    out[(size_t)bo * D + d] = (sqrtf(s) / (0.5f + s)) * acc;
  }
}

// Fused routing step, 32-n tile, 256 thr (4 waves), grid (B,32)=1024 blocks.
// Round-0 structure; phase 2 uses transpose-on-store u_T + b64 frag reads.
__global__ __launch_bounds__(256, 4) void k_route(const unsigned short* __restrict__ t_hi_g,
                                                  const unsigned short* __restrict__ t_lo_g,
                                                  const unsigned short* __restrict__ u_bf,
                                                  const float* __restrict__ ssq_part,
                                                  int slot,
                                                  unsigned short* __restrict__ Sp) {
  __shared__ __align__(16) unsigned short u_hi[32 * ST];   // 4608 B (u_T in ph2)
  __shared__ unsigned short t_hi[32 * ST], t_lo[32 * ST];  // 2x4608 B
  __shared__ float wv[32 * 36];                            // 4608 B logits
  __shared__ float psum[8 * 36];                           // softmax partials
  __shared__ float mbuf[36];
  unsigned short* wvh = t_hi;  // alias: t dead after phase 1
  unsigned short* wvl = t_lo;

  const int b = blockIdx.x, n0 = blockIdx.y * 32;
  const int tid = threadIdx.x, lane = tid & 63, wave = tid >> 6;
  const int m = lane & 15, oct = lane >> 4;
  const unsigned short* ubf = u_bf + ((size_t)b * N + n0) * K;
  const unsigned short* thg = t_hi_g + (size_t)b * O * K;
  const unsigned short* tlg = t_lo_g + (size_t)b * O * K;

  // staging index: 32 rows x 8 col-groups of 8 u16 (one uint4 per thread)
  const int sr = tid >> 3, sc8 = (tid & 7) * 8;
  const int scs = sc8 ^ swz(sr);  // swizzled LDS col

  // ---- phase 1: bb[32o][32n] = t . u^T ----
  const int mo = wave & 1, nt = wave >> 1;  // o-half, n-half (16x16 tiles)
  f32x4 accb = {0.f, 0.f, 0.f, 0.f};
  for (int kc = 0; kc < K; kc += 64) {
    __syncthreads();
    {
      const size_t go = (size_t)sr * K + kc + sc8;
      *(uint4*)&t_hi[sr * ST + scs] = *(const uint4*)&thg[go];
      *(uint4*)&t_lo[sr * ST + scs] = *(const uint4*)&tlg[go];
      *(uint4*)&u_hi[sr * ST + scs] = *(const uint4*)&ubf[go];
    }
    __syncthreads();
#pragma unroll
    for (int ks = 0; ks < 64; ks += 32) {
      bf16x8 ah = frag_row(t_hi, mo * 16 + m, ks + oct * 8);
      bf16x8 al = frag_row(t_lo, mo * 16 + m, ks + oct * 8);
      bf16x8 bh = frag_row(u_hi, nt * 16 + m, ks + oct * 8);
      accb = __builtin_amdgcn_mfma_f32_16x16x32_bf16(ah, bh, accb, 0, 0, 0);
      accb = __builtin_amdgcn_mfma_f32_16x16x32_bf16(al, bh, accb, 0, 0, 0);
    }
  }
  __syncthreads();
  // ---- global-norm reduction from ssq_part (1024 entries) ----
  {
    const float* sp = ssq_part + slot * 1024;
    float sa = 0.f;
#pragma unroll
    for (int j = 0; j < 4; j++) sa += sp[tid + j * 256];
    psum[tid & 255] = sa;
    __syncthreads();
    if (tid < 64) {
      float s = psum[tid] + psum[tid + 64] + psum[tid + 128] + psum[tid + 192];
#pragma unroll
      for (int mm = 32; mm >= 1; mm >>= 1) s += __shfl_xor(s, mm, 64);
      if (tid == 0) mbuf[0] = rsqrtf(fmaxf(s, 1e-12f));
    }
    __syncthreads();
  }
  const float nrm_inv = mbuf[0];
  __syncthreads();
#pragma unroll
  for (int r = 0; r < 4; r++)  // D: col=m (n), row=oct*4+r (o)
    wv[(mo * 16 + oct * 4 + r) * 36 + nt * 16 + m] = accb[r] * nrm_inv;
  __syncthreads();

  // ---- softmax over o, parallel: n=tid&31, g=tid>>5 owns 4 o's ----
  {
    int n = tid & 31, g = tid >> 5;
    float m4 = -1e30f;
#pragma unroll
    for (int j = 0; j < 4; j++) m4 = fmaxf(m4, wv[(g * 4 + j) * 36 + n]);
    psum[g * 36 + n] = m4;
    __syncthreads();
    if (tid < 32) {
      float mx = psum[tid];
#pragma unroll
      for (int gg = 1; gg < 8; gg++) mx = fmaxf(mx, psum[gg * 36 + tid]);
      mbuf[tid] = mx;
    }
    __syncthreads();
    float mx = mbuf[n];
    float s4 = 0.f;
#pragma unroll
    for (int j = 0; j < 4; j++) {
      float e = __expf(wv[(g * 4 + j) * 36 + n] - mx);
      wv[(g * 4 + j) * 36 + n] = e;
      s4 += e;
    }
    psum[g * 36 + n] = s4;
    __syncthreads();
    if (tid < 32) {
      float s = 0.f;
#pragma unroll
      for (int gg = 0; gg < 8; gg++) s += psum[gg * 36 + tid];
      mbuf[tid] = 1.f / s;
    }
    __syncthreads();
    float inv = mbuf[n];
#pragma unroll
    for (int j = 0; j < 4; j++) {  // Wv -> bf16 hi/lo into dead t region
      unsigned short h, l;
      split2(wv[(g * 4 + j) * 36 + n] * inv, h, l);
      wvh[(g * 4 + j) * ST + n] = h;
      wvl[(g * 4 + j) * ST + n] = l;
    }
  }
  __syncthreads();

  // ---- phase 2: Spart = Wv . u  (kred = n = 32, bf16 stores, no atomics).
  // u staged TRANSPOSED: u_T[c][n] stride STT=36 u16 in the u_hi buffer
  // (64*36 == 32*72). Frag = two aligned b64 reads of contiguous n. ----
  const int mo2 = wave & 1, kp = wave >> 1;  // o-half, ktile-pair
  const int o0 = mo2 * 16;
  bf16x8 a_h = *(const bf16x8*)&wvh[(o0 + m) * ST + oct * 8];
  bf16x8 a_l = *(const bf16x8*)&wvl[(o0 + m) * ST + oct * 8];
  unsigned short* Sb = Sp + ((size_t)b * NT + blockIdx.y) * O * K;
  for (int kc = 0; kc < K; kc += 64) {
    __syncthreads();
    {
      union { uint4 q; unsigned short s[8]; } v;
      v.q = *(const uint4*)&ubf[(size_t)sr * K + kc + sc8];
#pragma unroll
      for (int j = 0; j < 8; j++) u_hi[(sc8 + j) * STT + sr] = v.s[j];
    }
    __syncthreads();
#pragma unroll
    for (int kt = kp * 2; kt < kp * 2 + 2; kt++) {
      int c = kt * 16 + m;  // column within chunk
      union { bf16x8 v; uint2 q[2]; } uu;
      uu.q[0] = *(const uint2*)&u_hi[c * STT + oct * 8];
      uu.q[1] = *(const uint2*)&u_hi[c * STT + oct * 8 + 4];
      f32x4 acs = {0.f, 0.f, 0.f, 0.f};
      acs = __builtin_amdgcn_mfma_f32_16x16x32_bf16(a_h, uu.v, acs, 0, 0, 0);
      acs = __builtin_amdgcn_mfma_f32_16x16x32_bf16(a_l, uu.v, acs, 0, 0, 0);
#pragma unroll
      for (int r = 0; r < 4; r++)  // D: col=m -> kcol, row=oct*4+r -> o
        Sb[(size_t)(o0 + oct * 4 + r) * K + kc + c] = bf16_1(acs[r]);
    }
  }
}

extern "C" void kernel_launch(void* const* d_in, const int* in_sizes, int n_in,
                              void* d_out, int out_size, void* d_ws, size_t ws_size,
                              hipStream_t stream) {
  const float* u = (const float*)d_in[0];  // [B,N,K] f32
  const float* W = (const float*)d_in[1];  // [K,F] f32
  float* out = (float*)d_out;              // [B,O,D] f32

  char* ws = (char*)d_ws;
  unsigned short* Sp = (unsigned short*)ws;              // B*NT*O*K u16 (33.5MB)
  unsigned short* u_bf = Sp + (size_t)B * NT * O * K;    // B*N*K u16 (33.5MB)
  unsigned short* t_hi = u_bf + (size_t)B * N * K;       // B*O*K u16 (1MB)
  unsigned short* t_lo = t_hi + (size_t)B * O * K;       // B*O*K u16
  float* cs_part = (float*)(t_lo + (size_t)B * O * K);   // B*32*K f32 (2MB)
  float* ssq_part = cs_part + (size_t)B * 32 * K;        // 2048 f32

  k_prep<<<dim3(B, 32), 256, 0, stream>>>(u, cs_part, u_bf);
  k_vjt<<<B * O, 512, 0, stream>>>(Sp, cs_part, W, ssq_part, 0, t_hi, t_lo);
  k_route<<<dim3(B, NT), 256, 0, stream>>>(t_hi, t_lo, u_bf, ssq_part, 0, Sp);
  k_vjt<<<B * O, 512, 0, stream>>>(Sp, cs_part, W, ssq_part, 1, t_hi, t_lo);
  k_route<<<dim3(B, NT), 256, 0, stream>>>(t_hi, t_lo, u_bf, ssq_part, 1, Sp);
  k_out<<<B * O, 512, 0, stream>>>(Sp, W, out);
}